// Round 1
// 85.121 us; speedup vs baseline: 1.0306x; 1.0306x over previous
//
#include <hip/hip_runtime.h>
#include <math.h>

#define M_DIM 1024
#define N_DIM 1024
#define NRANK 64
#define BN 16   // n-tile per block
#define BF 64   // f-tile per block

typedef float f32x2 __attribute__((ext_vector_type(2)));

// Hf scratch, interleaved {re, im} so the hot loop reads one ds_read_b64 per term.
__device__ f32x2 g_Hf[NRANK * M_DIM];

__device__ __forceinline__ float softplus_f(float x) {
    return log1pf(__expf(x));
}

// v_sin_f32 / v_cos_f32: input in REVOLUTIONS (D = sin(S0*2pi)); |rev|<1 needs
// no range reduction. Single quarter-rate instruction each.
__device__ __forceinline__ float fast_sin_rev(float rev) {
#if __has_builtin(__builtin_amdgcn_sinf)
    return __builtin_amdgcn_sinf(rev);
#else
    return __sinf(rev * 6.28318530717958647f);
#endif
}
__device__ __forceinline__ float fast_cos_rev(float rev) {
#if __has_builtin(__builtin_amdgcn_cosf)
    return __builtin_amdgcn_cosf(rev);
#else
    return __cosf(rev * 6.28318530717958647f);
#endif
}

// ---------------------------------------------------------------------------
// Kernel 1: Hf[r, :] = FFT_1024( softplus(H[r, :]) )  (unchanged algorithm,
// output now interleaved float2)
// ---------------------------------------------------------------------------
__global__ __launch_bounds__(512) void fft_rows(const float* __restrict__ H) {
    __shared__ float sre[M_DIM];
    __shared__ float sim[M_DIM];
    const int r = blockIdx.x;
    const int tid = threadIdx.x;

    for (int j = tid; j < M_DIM; j += 512) {
        int src = __brev((unsigned)j) >> 22;   // 10-bit reverse
        sre[j] = softplus_f(H[r * M_DIM + src]);
        sim[j] = 0.0f;
    }
    __syncthreads();

    int log2half = 0;
    for (int len = 2; len <= M_DIM; len <<= 1, ++log2half) {
        const int half = len >> 1;
        const int j    = tid & (half - 1);
        const int base = (tid >> log2half) << (log2half + 1);
        const int i0   = base + j;
        const int i1   = i0 + half;
        const float rev = -(float)j / (float)len;   // (-0.5, 0], exact
        const float s = fast_sin_rev(rev);
        const float c = fast_cos_rev(rev);
        const float xr = sre[i1], xi = sim[i1];
        const float vr = xr * c - xi * s;
        const float vi = xr * s + xi * c;
        const float ur = sre[i0], ui = sim[i0];
        sre[i0] = ur + vr;  sim[i0] = ui + vi;
        sre[i1] = ur - vr;  sim[i1] = ui - vi;
        __syncthreads();
    }

    for (int j = tid; j < M_DIM; j += 512) {
        g_Hf[r * M_DIM + j] = (f32x2){sre[j], sim[j]};
    }
}

// ---------------------------------------------------------------------------
// Kernel 2: WHt[n,f] = sum_r softplus(W[n,r]) * e^{-2pi i f tau[n,r]/M} * Hf[r,f]
// PLANAR output (real plane then imag plane).
// Thread owns ONE n, FOUR f's (f = f0 + fbase + 16k). Phase at f advanced by
// precomputed per-(n,r) step e^{-2pi i a*16} -> trans ops per term: 0.5.
// v2: packed-fp32 complex math (v_pk_fma_f32): complex MAC = 2 pk-FMA,
// phase step = 2 pk ops; Hf as float2 (ds_read_b64), coeffs as float4
// (ds_read_b128). Per-rank issue count ~33 VALU + 12 LDS -> ~16 VALU + 5 LDS.
// ---------------------------------------------------------------------------
__global__ __launch_bounds__(256) void shiftnmf_main(
    const float* __restrict__ W, const float* __restrict__ tau,
    float* __restrict__ out, int out_elems) {

    __shared__ f32x2  shHf[NRANK][BF];       // 32 KB, {re,im} interleaved
    __shared__ float4 shC [NRANK][BN + 1];   // 17 KB, {a, wp, cos16, sin16}; +1 pad
                                             // keeps read broadcast conflict-free

    const int tid = threadIdx.x;
    const int f0  = blockIdx.x * BF;
    const int n0  = blockIdx.y * BN;

    for (int idx = tid; idx < NRANK * BF; idx += 256) {
        const int rr = idx >> 6, ff = idx & 63;
        shHf[rr][ff] = g_Hf[rr * M_DIM + f0 + ff];   // coalesced 8B/lane
    }
    for (int idx = tid; idx < BN * NRANK; idx += 256) {
        const int nn = idx >> 6, rr = idx & 63;      // rr fastest: coalesced W/tau
        const int n  = n0 + nn;
        const float wp = softplus_f(W[n * NRANK + rr]);
        const float a  = (-1.0f / (float)M_DIM) * tau[n * NRANK + rr];
        const float rev16 = a * 16.0f;               // |rev16| < 1/64
        shC[rr][nn] = make_float4(a, wp, fast_cos_rev(rev16), fast_sin_rev(rev16));
    }
    __syncthreads();

    const int fbase = tid & 15;                      // 0..15
    const int n_loc = tid >> 4;                      // 0..15
    const float fglob = (float)(f0 + fbase);

    f32x2 acc[4] = {{0.f, 0.f}, {0.f, 0.f}, {0.f, 0.f}, {0.f, 0.f}};

    for (int r = 0; r < NRANK; ++r) {
        const float4 cf = shC[r][n_loc];             // ds_read_b128, 4-addr bcast
        const float rev0 = cf.x * fglob;             // in (-1, 0]
        f32x2 p;                                     // phase with wp folded in
        p.x = cf.y * fast_cos_rev(rev0);
        p.y = cf.y * fast_sin_rev(rev0);
        const f32x2 st = {cf.z, cf.w};               // step e^{-2pi i a*16}
        #pragma unroll
        for (int k = 0; k < 4; ++k) {
            const f32x2 h = shHf[r][fbase + (k << 4)];  // ds_read_b64, 16 addrs
            const f32x2 pneg = {-p.y, p.y};
            // acc += p * h (complex): 2 x v_pk_fma_f32
            acc[k] = __builtin_elementwise_fma(pneg, (f32x2){h.y, h.x}, acc[k]);
            acc[k] = __builtin_elementwise_fma((f32x2){p.x, p.x}, h, acc[k]);
            if (k < 3) {
                // p *= st (complex): v_pk_mul + v_pk_fma
                const f32x2 t = pneg * (f32x2){st.y, st.x};
                p = __builtin_elementwise_fma((f32x2){p.x, p.x}, st, t);
            }
        }
    }

    #pragma unroll
    for (int k = 0; k < 4; ++k) {
        const int n  = n0 + n_loc;
        const int oi = n * M_DIM + f0 + fbase + (k << 4);
        if (oi < out_elems) out[oi] = acc[k].x;                      // real plane
        const int oj = N_DIM * M_DIM + oi;
        if (oj < out_elems) out[oj] = acc[k].y;                      // imag plane
    }
}

extern "C" void kernel_launch(void* const* d_in, const int* in_sizes, int n_in,
                              void* d_out, int out_size, void* d_ws, size_t ws_size,
                              hipStream_t stream) {
    const float* W   = (const float*)d_in[0];   // (1024, 64)
    const float* H   = (const float*)d_in[1];   // (64, 1024)
    const float* tau = (const float*)d_in[2];   // (1024, 64)

    (void)d_ws; (void)ws_size;

    fft_rows<<<NRANK, 512, 0, stream>>>(H);
    shiftnmf_main<<<dim3(M_DIM / BF, N_DIM / BN), 256, 0, stream>>>(
        W, tau, (float*)d_out, out_size);
}

// Round 2
// 84.972 us; speedup vs baseline: 1.0324x; 1.0018x over previous
//
#include <hip/hip_runtime.h>
#include <math.h>

#define M_DIM 1024
#define N_DIM 1024
#define NRANK 64
#define BN 16   // n-tile per block
#define BF 64   // f-tile per block

typedef float f32x2 __attribute__((ext_vector_type(2)));

// Hf scratch, interleaved {re, im} so the hot loop reads one ds_read_b64 per term.
__device__ f32x2 g_Hf[NRANK * M_DIM];
// Precomputed per-(n,r) coefficients {a, wp, cos16, sin16} — computed ONCE in the
// fft launch (16 extra blocks on otherwise-idle CUs) instead of 16x per f-block.
__device__ float4 g_C[N_DIM * NRANK];

__device__ __forceinline__ float softplus_f(float x) {
    return log1pf(__expf(x));
}

// v_sin_f32 / v_cos_f32: input in REVOLUTIONS (D = sin(S0*2pi)); |rev|<1 needs
// no range reduction. Single quarter-rate instruction each.
__device__ __forceinline__ float fast_sin_rev(float rev) {
#if __has_builtin(__builtin_amdgcn_sinf)
    return __builtin_amdgcn_sinf(rev);
#else
    return __sinf(rev * 6.28318530717958647f);
#endif
}
__device__ __forceinline__ float fast_cos_rev(float rev) {
#if __has_builtin(__builtin_amdgcn_cosf)
    return __builtin_amdgcn_cosf(rev);
#else
    return __cosf(rev * 6.28318530717958647f);
#endif
}

__device__ __forceinline__ f32x2 cmul(f32x2 a, float c, float s) {
    // a * (c + i s)
    return (f32x2){a.x * c - a.y * s, a.x * s + a.y * c};
}

// ---------------------------------------------------------------------------
// Kernel 1 (blocks 0..63): Hf[r, :] = FFT_1024( softplus(H[r, :]) )
// Radix-4 DIF, 5 stages. Stage 1 (len=1024) fused with the coalesced global
// load (real input -> cheap butterfly); stages len=256,64,16 in LDS (f32x2
// interleaved, b64 ops, in-place per-thread butterflies, 1 barrier/stage);
// final stage (len=4) fused with the store: results written digit-reversed
// directly to g_Hf (scatter, absorbed by L2 — g_Hf is only 512 KB).
// Blocks 64..79: coefficient precompute for kernel 2.
// ---------------------------------------------------------------------------
__global__ __launch_bounds__(256) void fft_rows(
    const float* __restrict__ H, const float* __restrict__ W,
    const float* __restrict__ tau) {

    const int b   = blockIdx.x;
    const int t   = threadIdx.x;

    if (b >= NRANK) {
        // ---- coefficient precompute: 16 blocks x 256 threads x 16 elems ----
        const int base = (b - NRANK) * (256 * 16) + t;
        #pragma unroll
        for (int it = 0; it < 16; ++it) {
            const int idx = base + it * 256;          // idx = n*64 + r, coalesced
            const float wp = softplus_f(W[idx]);
            const float a  = (-1.0f / (float)M_DIM) * tau[idx];
            const float rev16 = a * 16.0f;            // |rev16| < 1/64
            g_C[idx] = make_float4(a, wp, fast_cos_rev(rev16), fast_sin_rev(rev16));
        }
        return;
    }

    __shared__ f32x2 s[M_DIM];   // 8 KB
    const int r = b;

    // ---- stage len=1024 (q=256), fused with load; input is real ----
    {
        const float v0 = softplus_f(H[r * M_DIM + t]);
        const float v1 = softplus_f(H[r * M_DIM + t + 256]);
        const float v2 = softplus_f(H[r * M_DIM + t + 512]);
        const float v3 = softplus_f(H[r * M_DIM + t + 768]);
        const float u0 = v0 + v2, u1 = v0 - v2;
        const float u2 = v1 + v3, u3 = v1 - v3;
        const float j1 = -(float)t * (1.0f / 1024.0f);      // in (-0.25, 0]
        const float c1 = fast_cos_rev(j1),        s1 = fast_sin_rev(j1);
        const float c2 = fast_cos_rev(2.0f * j1), s2 = fast_sin_rev(2.0f * j1);
        const float c3 = fast_cos_rev(3.0f * j1), s3 = fast_sin_rev(3.0f * j1);
        // z0 = u0+u2 ; z1 = (u1 - i u3) W^j ; z2 = (u0-u2) W^2j ; z3 = (u1 + i u3) W^3j
        s[t]       = (f32x2){u0 + u2, 0.0f};
        s[t + 256] = (f32x2){u1 * c1 + u3 * s1, u1 * s1 - u3 * c1};
        s[t + 512] = (f32x2){(u0 - u2) * c2,    (u0 - u2) * s2};
        s[t + 768] = (f32x2){u1 * c3 - u3 * s3, u1 * s3 + u3 * c3};
    }
    __syncthreads();

    // ---- mid stages: len = 256, 64, 16 ----
    #pragma unroll
    for (int stage = 0; stage < 3; ++stage) {
        const int log2q = 6 - 2 * stage;                    // 6, 4, 2
        const int q     = 1 << log2q;                       // 64, 16, 4
        const int j     = t & (q - 1);
        const int i0    = ((t >> log2q) << (log2q + 2)) + j;
        const f32x2 a = s[i0], bb = s[i0 + q], c = s[i0 + 2 * q], d = s[i0 + 3 * q];
        const f32x2 u0 = a + c, u1 = a - c, u2 = bb + d, u3 = bb - d;
        const float jr = -(float)j / (float)(4 << log2q);   // -j/len
        const float c1 = fast_cos_rev(jr),        s1 = fast_sin_rev(jr);
        const float c2 = fast_cos_rev(2.0f * jr), s2 = fast_sin_rev(2.0f * jr);
        const float c3 = fast_cos_rev(3.0f * jr), s3 = fast_sin_rev(3.0f * jr);
        const f32x2 m1 = {u1.x + u3.y, u1.y - u3.x};        // u1 - i u3
        const f32x2 m3 = {u1.x - u3.y, u1.y + u3.x};        // u1 + i u3
        // in-place: this thread reads and writes the same 4 slots — barrier
        // only needed between stages.
        s[i0]         = u0 + u2;
        s[i0 + q]     = cmul(m1, c1, s1);
        s[i0 + 2*q]   = cmul(u0 - u2, c2, s2);
        s[i0 + 3*q]   = cmul(m3, c3, s3);
        __syncthreads();
    }

    // ---- final stage len=4 (no twiddles), fused with digit-reversed store ----
    {
        const float4* s4 = reinterpret_cast<const float4*>(s);
        const float4 p0 = s4[2 * t];          // elems 4t, 4t+1
        const float4 p1 = s4[2 * t + 1];      // elems 4t+2, 4t+3
        const f32x2 a = {p0.x, p0.y}, bb = {p0.z, p0.w};
        const f32x2 c = {p1.x, p1.y}, d  = {p1.z, p1.w};
        const f32x2 u0 = a + c, u1 = a - c, u2 = bb + d, u3 = bb - d;
        const f32x2 z0 = u0 + u2;
        const f32x2 z1 = {u1.x + u3.y, u1.y - u3.x};   // u1 - i u3
        const f32x2 z2 = u0 - u2;
        const f32x2 z3 = {u1.x - u3.y, u1.y + u3.x};   // u1 + i u3
        // output position of slot (4t+m) is digit-reverse_4(4t+m) = m*256 + dr(t)
        const int dr = ((t & 3) << 6) | (((t >> 2) & 3) << 4) |
                       (((t >> 4) & 3) << 2) | ((t >> 6) & 3);
        f32x2* __restrict__ o = g_Hf + r * M_DIM + dr;
        o[0]   = z0;
        o[256] = z1;
        o[512] = z2;
        o[768] = z3;
    }
}

// ---------------------------------------------------------------------------
// Kernel 2: WHt[n,f] = sum_r softplus(W[n,r]) * e^{-2pi i f tau[n,r]/M} * Hf[r,f]
// PLANAR output (real plane then imag plane).
// Thread owns ONE n, FOUR f's (f = f0 + fbase + 16k). Phase at f advanced by
// precomputed per-(n,r) step e^{-2pi i a*16} -> trans ops per term: 0.5.
// Packed-fp32 complex math (v_pk_fma_f32); Hf as float2 (ds_read_b64), coeffs
// as float4 (ds_read_b128). v3: coefficients precomputed in kernel 1 — staging
// here is a pure coalesced float4 copy (no softplus/trans per f-block).
// ---------------------------------------------------------------------------
__global__ __launch_bounds__(256) void shiftnmf_main(
    float* __restrict__ out, int out_elems) {

    __shared__ f32x2  shHf[NRANK][BF];       // 32 KB, {re,im} interleaved
    __shared__ float4 shC [NRANK][BN + 1];   // 17 KB, {a, wp, cos16, sin16}; +1 pad

    const int tid = threadIdx.x;
    const int f0  = blockIdx.x * BF;
    const int n0  = blockIdx.y * BN;

    for (int idx = tid; idx < NRANK * BF; idx += 256) {
        const int rr = idx >> 6, ff = idx & 63;
        shHf[rr][ff] = g_Hf[rr * M_DIM + f0 + ff];   // coalesced 8B/lane
    }
    for (int idx = tid; idx < BN * NRANK; idx += 256) {
        const int nn = idx >> 6, rr = idx & 63;      // rr fastest: coalesced
        shC[rr][nn] = g_C[(n0 + nn) * NRANK + rr];   // b128 copy
    }
    __syncthreads();

    const int fbase = tid & 15;                      // 0..15
    const int n_loc = tid >> 4;                      // 0..15
    const float fglob = (float)(f0 + fbase);

    f32x2 acc[4] = {{0.f, 0.f}, {0.f, 0.f}, {0.f, 0.f}, {0.f, 0.f}};

    for (int r = 0; r < NRANK; ++r) {
        const float4 cf = shC[r][n_loc];             // ds_read_b128, 4-addr bcast
        const float rev0 = cf.x * fglob;             // in (-1, 0]
        f32x2 p;                                     // phase with wp folded in
        p.x = cf.y * fast_cos_rev(rev0);
        p.y = cf.y * fast_sin_rev(rev0);
        const f32x2 st = {cf.z, cf.w};               // step e^{-2pi i a*16}
        #pragma unroll
        for (int k = 0; k < 4; ++k) {
            const f32x2 h = shHf[r][fbase + (k << 4)];  // ds_read_b64, 16 addrs
            const f32x2 pneg = {-p.y, p.y};
            // acc += p * h (complex): 2 x v_pk_fma_f32
            acc[k] = __builtin_elementwise_fma(pneg, (f32x2){h.y, h.x}, acc[k]);
            acc[k] = __builtin_elementwise_fma((f32x2){p.x, p.x}, h, acc[k]);
            if (k < 3) {
                // p *= st (complex): v_pk_mul + v_pk_fma
                const f32x2 tswap = pneg * (f32x2){st.y, st.x};
                p = __builtin_elementwise_fma((f32x2){p.x, p.x}, st, tswap);
            }
        }
    }

    #pragma unroll
    for (int k = 0; k < 4; ++k) {
        const int n  = n0 + n_loc;
        const int oi = n * M_DIM + f0 + fbase + (k << 4);
        if (oi < out_elems) out[oi] = acc[k].x;                      // real plane
        const int oj = N_DIM * M_DIM + oi;
        if (oj < out_elems) out[oj] = acc[k].y;                      // imag plane
    }
}

extern "C" void kernel_launch(void* const* d_in, const int* in_sizes, int n_in,
                              void* d_out, int out_size, void* d_ws, size_t ws_size,
                              hipStream_t stream) {
    const float* W   = (const float*)d_in[0];   // (1024, 64)
    const float* H   = (const float*)d_in[1];   // (64, 1024)
    const float* tau = (const float*)d_in[2];   // (1024, 64)

    (void)d_ws; (void)ws_size;

    fft_rows<<<NRANK + 16, 256, 0, stream>>>(H, W, tau);
    shiftnmf_main<<<dim3(M_DIM / BF, N_DIM / BN), 256, 0, stream>>>(
        (float*)d_out, out_size);
}